// Round 1
// baseline (2214.054 us; speedup 1.0000x reference)
//
#include <hip/hip_runtime.h>
#include <math.h>

#define B_ 4
#define C_ 256
#define CI_ 128
#define N_ 4096
constexpr float EPS_ = 1e-5f;

// ---------------- K0: zero BN accumulators (ws is poisoned each call) ----
__global__ void zero_acc(float* __restrict__ sums) {
    int t = threadIdx.x;           // 256 threads, 512 floats
    sums[t] = 0.f;
    sums[t + 256] = 0.f;
}

// ---------------- K1: g conv: gx[b][o][m] = sum_c g_w[o][c] x[b][c][m] + g_b[o]
__global__ __launch_bounds__(256) void gconv(const float* __restrict__ x,
                                             const float* __restrict__ gw,
                                             const float* __restrict__ gb,
                                             float* __restrict__ gx) {
    int m  = blockIdx.x * 256 + threadIdx.x;
    int o0 = blockIdx.y * 8;
    int b  = blockIdx.z;
    const float* xb = x + (size_t)b * C_ * N_;
    float acc[8];
#pragma unroll
    for (int k = 0; k < 8; k++) acc[k] = gb[o0 + k];
    for (int c = 0; c < C_; c++) {
        float xv = xb[c * N_ + m];            // coalesced along m
#pragma unroll
        for (int k = 0; k < 8; k++) acc[k] += gw[(o0 + k) * C_ + c] * xv;  // uniform -> s_load
    }
    float* gxb = gx + (size_t)b * CI_ * N_;
#pragma unroll
    for (int k = 0; k < 8; k++) gxb[(o0 + k) * N_ + m] = acc[k];          // coalesced
}

// ---------------- K2: flash attention (fp32, online softmax) -------------
// Per block: b = blockIdx.y, 64 query rows n0..n0+63. Block = 256 threads
// as (tx=0..15 -> 4 m-cols / 8 o-cols, ty=0..15 -> 4 n-rows).
// LDS: Qs[32][64], Ks[32][64] fp32 c-chunks; Ps[64][68], Vs[128][68]
// (pad 68 keeps float4 aligned, <=2-way bank aliasing).
__global__ __launch_bounds__(256) void attn(const float* __restrict__ x,
                                            const float* __restrict__ gx,
                                            float* __restrict__ y) {
    __shared__ float Qs[32 * 64];
    __shared__ float Ks[32 * 64];
    __shared__ float Ps[64 * 68];
    __shared__ float Vs[128 * 68];
    __shared__ float red[64 * 16];
    __shared__ float mrun[64], lrun[64], alpha_s[64];

    const int tid = threadIdx.x;
    const int tx = tid & 15, ty = tid >> 4;
    const int b  = blockIdx.y;
    const int n0 = blockIdx.x * 64;
    const float* xb  = x  + (size_t)b * C_ * N_;
    const float* gxb = gx + (size_t)b * CI_ * N_;

    if (tid < 64) { mrun[tid] = -INFINITY; lrun[tid] = 0.f; }

    float yacc[4][8];
#pragma unroll
    for (int i = 0; i < 4; i++)
#pragma unroll
        for (int j = 0; j < 8; j++) yacc[i][j] = 0.f;

    for (int m0 = 0; m0 < N_; m0 += 64) {
        // ---- S = Q Kt over C in chunks of 32 ----
        float s[4][4];
#pragma unroll
        for (int i = 0; i < 4; i++)
#pragma unroll
            for (int j = 0; j < 4; j++) s[i][j] = 0.f;

        for (int c0 = 0; c0 < C_; c0 += 32) {
            __syncthreads();
            {
                int nn = tid & 63, cb = tid >> 6;      // 4 c-rows per pass
#pragma unroll
                for (int r = 0; r < 8; r++) {
                    int cc = cb * 8 + r;
                    Qs[cc * 64 + nn] = xb[(c0 + cc) * N_ + n0 + nn];
                    Ks[cc * 64 + nn] = xb[(c0 + cc) * N_ + m0 + nn];
                }
            }
            __syncthreads();
#pragma unroll
            for (int cc = 0; cc < 32; cc++) {
                float4 qv = *(const float4*)&Qs[cc * 64 + 4 * ty];
                float4 kv = *(const float4*)&Ks[cc * 64 + 4 * tx];
                float qa[4] = {qv.x, qv.y, qv.z, qv.w};
                float ka[4] = {kv.x, kv.y, kv.z, kv.w};
#pragma unroll
                for (int i = 0; i < 4; i++)
#pragma unroll
                    for (int j = 0; j < 4; j++) s[i][j] += qa[i] * ka[j];
            }
        }

        // ---- online softmax: row max ----
#pragma unroll
        for (int i = 0; i < 4; i++) {
            float lm = fmaxf(fmaxf(s[i][0], s[i][1]), fmaxf(s[i][2], s[i][3]));
            red[(4 * ty + i) * 16 + tx] = lm;
        }
        __syncthreads();
        if (tid < 64) {
            float rm = -INFINITY;
#pragma unroll
            for (int k = 0; k < 16; k++) rm = fmaxf(rm, red[tid * 16 + k]);
            float mold = mrun[tid];
            float mnew = fmaxf(mold, rm);
            float a = __expf(mold - mnew);
            alpha_s[tid] = a;
            mrun[tid] = mnew;
            lrun[tid] *= a;
        }
        __syncthreads();

        // ---- P = exp(S - m), rescale y, stash P in LDS ----
#pragma unroll
        for (int i = 0; i < 4; i++) {
            int row = 4 * ty + i;
            float mcur = mrun[row];
            float a = alpha_s[row];
#pragma unroll
            for (int j = 0; j < 8; j++) yacc[i][j] *= a;
            float4 pv;
            pv.x = __expf(s[i][0] - mcur);
            pv.y = __expf(s[i][1] - mcur);
            pv.z = __expf(s[i][2] - mcur);
            pv.w = __expf(s[i][3] - mcur);
            *(float4*)&Ps[row * 68 + 4 * tx] = pv;
            red[row * 16 + tx] = pv.x + pv.y + pv.z + pv.w;
        }
        __syncthreads();

        // ---- l update + stage V tile ----
        if (tid < 64) {
            float sm = 0.f;
#pragma unroll
            for (int k = 0; k < 16; k++) sm += red[tid * 16 + k];
            lrun[tid] += sm;
        }
        {
            int mm = tid & 63, ob = tid >> 6;
#pragma unroll
            for (int r = 0; r < 32; r++) {
                int o = ob * 32 + r;
                Vs[o * 68 + mm] = gxb[o * N_ + m0 + mm];   // coalesced 64-runs
            }
        }
        __syncthreads();

        // ---- y += P V ----
        for (int mb = 0; mb < 16; mb++) {
            float pa[4][4], va[8][4];
#pragma unroll
            for (int i = 0; i < 4; i++) {
                float4 t = *(const float4*)&Ps[(4 * ty + i) * 68 + 4 * mb];
                pa[i][0] = t.x; pa[i][1] = t.y; pa[i][2] = t.z; pa[i][3] = t.w;
            }
#pragma unroll
            for (int j = 0; j < 8; j++) {
                float4 t = *(const float4*)&Vs[(tx + 16 * j) * 68 + 4 * mb];
                va[j][0] = t.x; va[j][1] = t.y; va[j][2] = t.z; va[j][3] = t.w;
            }
#pragma unroll
            for (int i = 0; i < 4; i++)
#pragma unroll
                for (int j = 0; j < 8; j++)
#pragma unroll
                    for (int t = 0; t < 4; t++) yacc[i][j] += pa[i][t] * va[j][t];
        }
    }

    // ---- epilogue: y /= l, transpose via LDS, coalesced write ----
    __syncthreads();
#pragma unroll
    for (int i = 0; i < 4; i++) {
        int row = 4 * ty + i;
        float inv = 1.f / lrun[row];
#pragma unroll
        for (int j = 0; j < 8; j++) Vs[(tx + 16 * j) * 68 + row] = yacc[i][j] * inv;
    }
    __syncthreads();
    {
        int nn = tid & 63, ob = tid >> 6;
        float* yb = y + (size_t)b * CI_ * N_;
#pragma unroll
        for (int r = 0; r < 32; r++) {
            int o = ob * 32 + r;
            yb[o * N_ + n0 + nn] = Vs[o * 68 + nn];        // coalesced
        }
    }
}

// ---------------- K3a: W conv + BN partial sums --------------------------
__global__ __launch_bounds__(256) void wconv_stats(const float* __restrict__ y,
                                                   const float* __restrict__ Ww,
                                                   const float* __restrict__ Wb,
                                                   float* __restrict__ wy,
                                                   float* __restrict__ sums) {
    int n   = blockIdx.x * 256 + threadIdx.x;
    int co0 = blockIdx.y * 4;
    int b   = blockIdx.z;
    const float* yb = y + (size_t)b * CI_ * N_;
    float acc[4];
#pragma unroll
    for (int k = 0; k < 4; k++) acc[k] = Wb[co0 + k];
    for (int o = 0; o < CI_; o++) {
        float yv = yb[o * N_ + n];
#pragma unroll
        for (int k = 0; k < 4; k++) acc[k] += Ww[(co0 + k) * CI_ + o] * yv;
    }
    float* wyb = wy + (size_t)b * C_ * N_;
#pragma unroll
    for (int k = 0; k < 4; k++) wyb[(co0 + k) * N_ + n] = acc[k];

    // per-channel sum / sumsq reduction: wave shuffle then 1 atomic per block
    __shared__ float wred[8][4];
    int lane = threadIdx.x & 63, wid = threadIdx.x >> 6;
#pragma unroll
    for (int k = 0; k < 4; k++) {
        float v1 = acc[k], v2 = acc[k] * acc[k];
#pragma unroll
        for (int off = 32; off > 0; off >>= 1) {
            v1 += __shfl_down(v1, off, 64);
            v2 += __shfl_down(v2, off, 64);
        }
        if (lane == 0) { wred[k][wid] = v1; wred[4 + k][wid] = v2; }
    }
    __syncthreads();
    if (threadIdx.x < 8) {
        int q = threadIdx.x;
        float t = wred[q][0] + wred[q][1] + wred[q][2] + wred[q][3];
        int k = q & 3;
        if (q < 4) atomicAdd(&sums[co0 + k], t);
        else       atomicAdd(&sums[256 + co0 + k], t);
    }
}

// ---------------- K3b: BN finalize + residual ----------------------------
__global__ __launch_bounds__(256) void bn_finalize(const float* __restrict__ wy,
                                                   const float* __restrict__ x,
                                                   const float* __restrict__ sums,
                                                   const float* __restrict__ gamma,
                                                   const float* __restrict__ beta,
                                                   float* __restrict__ out) {
    int n  = blockIdx.x * 256 + threadIdx.x;
    int co = blockIdx.y;
    int b  = blockIdx.z;
    float cnt  = (float)(B_ * N_);
    float mean = sums[co] / cnt;
    float var  = sums[256 + co] / cnt - mean * mean;
    float sc   = rsqrtf(var + EPS_) * gamma[co];
    size_t idx = ((size_t)b * C_ + co) * N_ + n;
    out[idx] = (wy[idx] - mean) * sc + beta[co] + x[idx];
}

extern "C" void kernel_launch(void* const* d_in, const int* in_sizes, int n_in,
                              void* d_out, int out_size, void* d_ws, size_t ws_size,
                              hipStream_t stream) {
    const float* x     = (const float*)d_in[0];
    const float* gw    = (const float*)d_in[1];
    const float* gb    = (const float*)d_in[2];
    const float* Ww    = (const float*)d_in[3];
    const float* Wb    = (const float*)d_in[4];
    const float* gamma = (const float*)d_in[5];
    const float* beta  = (const float*)d_in[6];
    float* out = (float*)d_out;
    float* ws  = (float*)d_ws;

    float* gx   = ws;                 // 4*128*4096 = 2,097,152 floats
    float* y    = ws + 2097152;       // 2,097,152 floats
    float* wy   = ws + 4194304;       // 4,194,304 floats
    float* sums = ws + 8388608;       // 512 floats (sum | sumsq)

    hipLaunchKernelGGL(zero_acc, dim3(1), dim3(256), 0, stream, sums);
    hipLaunchKernelGGL(gconv, dim3(N_ / 256, CI_ / 8, B_), dim3(256), 0, stream,
                       x, gw, gb, gx);
    hipLaunchKernelGGL(attn, dim3(N_ / 64, B_), dim3(256), 0, stream, x, gx, y);
    hipLaunchKernelGGL(wconv_stats, dim3(N_ / 256, C_ / 4, B_), dim3(256), 0, stream,
                       y, Ww, Wb, wy, sums);
    hipLaunchKernelGGL(bn_finalize, dim3(N_ / 256, C_, B_), dim3(256), 0, stream,
                       wy, x, sums, gamma, beta, out);
}

// Round 3
// 346.299 us; speedup vs baseline: 6.3935x; 6.3935x over previous
//
#include <hip/hip_runtime.h>
#include <math.h>

#define B_ 4
#define C_ 256
#define CI_ 128
#define N_ 4096
#define QT_ 128
#define KT_ 64
#define KH_ 2048
#define KSTRIDE 264   // 256 + 8 pad: lane row-stride = 132 dwords = 4 mod 32 -> 2-way (free)
#define VSTRIDE 72    // 64 + 8 pad:  lane row-stride = 36 dwords  = 4 mod 32 -> 2-way (free)
constexpr float EPS_ = 1e-5f;

typedef __attribute__((ext_vector_type(8))) short bfrag;
typedef __attribute__((ext_vector_type(4))) float f4;

__device__ __forceinline__ unsigned short bf16r(float x) {
    unsigned u = __float_as_uint(x);
    u += 0x7FFFu + ((u >> 16) & 1u);
    return (unsigned short)(u >> 16);
}
// pack (lo=a, hi=b) as two RNE bf16 in one u32
__device__ __forceinline__ unsigned pack_bf16(float a, float b) {
    unsigned ua = __float_as_uint(a); ua += 0x7FFFu + ((ua >> 16) & 1u);
    unsigned ub = __float_as_uint(b); ub += 0x7FFFu + ((ub >> 16) & 1u);
    return (ua >> 16) | (ub & 0xFFFF0000u);
}

// ---------------- K0: zero BN accumulators -------------------------------
__global__ void zero_acc(float* __restrict__ sums) {
    int t = threadIdx.x;
    sums[t] = 0.f;
    sums[t + 256] = 0.f;
}

// ---------------- K1: x[b][c][n] fp32 -> xt[b][n][c] bf16 ----------------
__global__ __launch_bounds__(256) void make_xt(const float* __restrict__ x,
                                               unsigned short* __restrict__ xt) {
    int n  = blockIdx.x * 256 + threadIdx.x;
    int c0 = blockIdx.y * 8;
    int b  = blockIdx.z;
    const float* xb = x + (size_t)b * C_ * N_;
    unsigned short buf[8];
#pragma unroll
    for (int c = 0; c < 8; c++) buf[c] = bf16r(xb[(c0 + c) * N_ + n]);   // coalesced
    uint4 v;
    v.x = buf[0] | ((unsigned)buf[1] << 16);
    v.y = buf[2] | ((unsigned)buf[3] << 16);
    v.z = buf[4] | ((unsigned)buf[5] << 16);
    v.w = buf[6] | ((unsigned)buf[7] << 16);
    *(uint4*)&xt[((size_t)b * N_ + n) * C_ + c0] = v;
}

// ---------------- K2: g conv from xt -> gx bf16 [b][o][m] ----------------
__global__ __launch_bounds__(256) void gconv(const unsigned short* __restrict__ xt,
                                             const float* __restrict__ gw,
                                             const float* __restrict__ gb,
                                             unsigned short* __restrict__ gx) {
    int m  = blockIdx.x * 256 + threadIdx.x;
    int o0 = blockIdx.y * 16;
    int b  = blockIdx.z;
    const uint4* xr = (const uint4*)(xt + ((size_t)b * N_ + m) * C_);
    float acc[16];
#pragma unroll
    for (int o = 0; o < 16; o++) acc[o] = gb[o0 + o];
    for (int cb = 0; cb < C_ / 8; cb++) {
        uint4 u = xr[cb];
        float xv[8];
        xv[0] = __uint_as_float(u.x << 16); xv[1] = __uint_as_float(u.x & 0xFFFF0000u);
        xv[2] = __uint_as_float(u.y << 16); xv[3] = __uint_as_float(u.y & 0xFFFF0000u);
        xv[4] = __uint_as_float(u.z << 16); xv[5] = __uint_as_float(u.z & 0xFFFF0000u);
        xv[6] = __uint_as_float(u.w << 16); xv[7] = __uint_as_float(u.w & 0xFFFF0000u);
#pragma unroll
        for (int o = 0; o < 16; o++) {
            const float* gwr = gw + (size_t)(o0 + o) * C_ + cb * 8;   // uniform -> s_load
#pragma unroll
            for (int cc = 0; cc < 8; cc++) acc[o] += gwr[cc] * xv[cc];
        }
    }
#pragma unroll
    for (int o = 0; o < 16; o++)
        gx[((size_t)b * CI_ + o0 + o) * N_ + m] = bf16r(acc[o]);       // coalesced
}

// ---------------- K3: MFMA flash attention (bf16, split-K halves) --------
// block: 256 thr = 4 waves; 128 q rows, one K-half (2048 keys).
// St[m][q] = K.Q (A=Ks LDS, B=Q regs); P -> Ps[q][m] LDS; Yt[ci][q] = Vt.P.
// Plain padded LDS layouts, register staging (m92-verified patterns only).
__global__ __launch_bounds__(256, 2) void attn(const unsigned short* __restrict__ xt,
                                               const unsigned short* __restrict__ gx,
                                               float* __restrict__ Yp,
                                               float* __restrict__ ml) {
    __shared__ __align__(16) unsigned short Ks[64 * KSTRIDE];    // 33 KB
    __shared__ __align__(16) unsigned short Vs[128 * VSTRIDE];   // 18 KB
    __shared__ __align__(16) unsigned short Ps[128 * VSTRIDE];   // 18 KB

    const int tid  = threadIdx.x;
    const int lane = tid & 63, w = tid >> 6;
    const int quad = lane >> 4, ql = lane & 15;
    const int half = blockIdx.x & 1;
    const int b    = (blockIdx.x & 7) >> 1;      // XCD spread per batch
    const int qt   = blockIdx.x >> 3;
    const int n0   = qt * QT_;
    const int kbase = half * KH_;
    const unsigned short* xtb = xt + (size_t)b * N_ * C_;
    const unsigned short* gxb = gx + (size_t)b * CI_ * N_;

    // Q B-frags: loop-invariant, in registers (64 VGPRs)
    bfrag qb[2][8];
#pragma unroll
    for (int t = 0; t < 2; t++)
#pragma unroll
        for (int ks = 0; ks < 8; ks++)
            qb[t][ks] = *(const bfrag*)(xtb + (size_t)(n0 + 32 * w + 16 * t + ql) * C_
                                        + 32 * ks + quad * 8);

    f4 yacc[8][2];
    const f4 zero4 = {0.f, 0.f, 0.f, 0.f};
#pragma unroll
    for (int i = 0; i < 8; i++) { yacc[i][0] = zero4; yacc[i][1] = zero4; }
    float mrun[2] = {-INFINITY, -INFINITY};
    float lrun[2] = {0.f, 0.f};

    for (int it = 0; it < KH_ / KT_; ++it) {
        const int m0 = kbase + it * KT_;

        // ---- stage K (64x256) and V (128x64) via registers ----
        uint4 kreg[8], vreg[4];
#pragma unroll
        for (int r = 0; r < 8; r++) {
            int row = 8 * r + (tid >> 5), blk = tid & 31;
            kreg[r] = *(const uint4*)(xtb + (size_t)(m0 + row) * C_ + blk * 8);
        }
#pragma unroll
        for (int r = 0; r < 4; r++) {
            int row = 32 * r + (tid >> 3), blk = tid & 7;
            vreg[r] = *(const uint4*)(gxb + (size_t)row * N_ + m0 + blk * 8);
        }
        __syncthreads();                       // prev-iter LDS reads done
#pragma unroll
        for (int r = 0; r < 8; r++) {
            int row = 8 * r + (tid >> 5), blk = tid & 31;
            *(uint4*)&Ks[row * KSTRIDE + blk * 8] = kreg[r];
        }
#pragma unroll
        for (int r = 0; r < 4; r++) {
            int row = 32 * r + (tid >> 3), blk = tid & 7;
            *(uint4*)&Vs[row * VSTRIDE + blk * 8] = vreg[r];
        }
        __syncthreads();                       // tiles visible

        // ---- St = K.Q : 64 mfma / wave ----
        f4 sacc[4][2];
#pragma unroll
        for (int i = 0; i < 4; i++) { sacc[i][0] = zero4; sacc[i][1] = zero4; }
#pragma unroll
        for (int ks = 0; ks < 8; ks++) {
            bfrag ka[4];
#pragma unroll
            for (int i = 0; i < 4; i++)
                ka[i] = *(const bfrag*)&Ks[(16 * i + ql) * KSTRIDE + 32 * ks + quad * 8];
#pragma unroll
            for (int i = 0; i < 4; i++) {
                sacc[i][0] = __builtin_amdgcn_mfma_f32_16x16x32_bf16(ka[i], qb[0][ks], sacc[i][0], 0, 0, 0);
                sacc[i][1] = __builtin_amdgcn_mfma_f32_16x16x32_bf16(ka[i], qb[1][ks], sacc[i][1], 0, 0, 0);
            }
        }

        // ---- online softmax over m (in-lane + cross-quad shuffles) ----
        float alpha[2];
#pragma unroll
        for (int t = 0; t < 2; t++) {
            float mx = -INFINITY;
#pragma unroll
            for (int i = 0; i < 4; i++)
#pragma unroll
                for (int r = 0; r < 4; r++) mx = fmaxf(mx, sacc[i][t][r]);
            mx = fmaxf(mx, __shfl_xor(mx, 16, 64));
            mx = fmaxf(mx, __shfl_xor(mx, 32, 64));
            float mn = fmaxf(mrun[t], mx);
            alpha[t] = __expf(mrun[t] - mn);   // -inf -> 0 first iter
            mrun[t] = mn;
            lrun[t] *= alpha[t];
        }
        if (__any(alpha[0] != 1.f || alpha[1] != 1.f)) {
#pragma unroll
            for (int i = 0; i < 8; i++)
#pragma unroll
                for (int t = 0; t < 2; t++) {
                    yacc[i][t][0] *= alpha[t]; yacc[i][t][1] *= alpha[t];
                    yacc[i][t][2] *= alpha[t]; yacc[i][t][3] *= alpha[t];
                }
        }

        // ---- P = exp(S-m): pack bf16 pairs -> Ps[q][m] (wave-private rows) ----
        float lsum[2] = {0.f, 0.f};
#pragma unroll
        for (int t = 0; t < 2; t++) {
            int q = 32 * w + 16 * t + ql;
#pragma unroll
            for (int i = 0; i < 4; i++) {
                float p0 = __expf(sacc[i][t][0] - mrun[t]);
                float p1 = __expf(sacc[i][t][1] - mrun[t]);
                float p2 = __expf(sacc[i][t][2] - mrun[t]);
                float p3 = __expf(sacc[i][t][3] - mrun[t]);
                lsum[t] += (p0 + p1) + (p2 + p3);
                int idx = q * VSTRIDE + 16 * i + 4 * quad;   // m = 16i+4*quad+r
                *(unsigned*)&Ps[idx]     = pack_bf16(p0, p1);
                *(unsigned*)&Ps[idx + 2] = pack_bf16(p2, p3);
            }
        }
#pragma unroll
        for (int t = 0; t < 2; t++) {
            lsum[t] += __shfl_xor(lsum[t], 16, 64);
            lsum[t] += __shfl_xor(lsum[t], 32, 64);
            lrun[t] += lsum[t];
        }

        // ---- Yt += Vt.P : 32 mfma / wave ----
#pragma unroll
        for (int ks = 0; ks < 2; ks++) {
            bfrag pb[2], va[8];
#pragma unroll
            for (int t = 0; t < 2; t++)
                pb[t] = *(const bfrag*)&Ps[(32 * w + 16 * t + ql) * VSTRIDE + 32 * ks + quad * 8];
#pragma unroll
            for (int i = 0; i < 8; i++)
                va[i] = *(const bfrag*)&Vs[(16 * i + ql) * VSTRIDE + 32 * ks + quad * 8];
#pragma unroll
            for (int i = 0; i < 8; i++) {
                yacc[i][0] = __builtin_amdgcn_mfma_f32_16x16x32_bf16(va[i], pb[0], yacc[i][0], 0, 0, 0);
                yacc[i][1] = __builtin_amdgcn_mfma_f32_16x16x32_bf16(va[i], pb[1], yacc[i][1], 0, 0, 0);
            }
        }
    }

    // ---- epilogue: store numerator partial + (m,l) ----
#pragma unroll
    for (int i = 0; i < 8; i++)
#pragma unroll
        for (int t = 0; t < 2; t++) {
            int n = n0 + 32 * w + 16 * t + ql;
#pragma unroll
            for (int r = 0; r < 4; r++) {
                int ci = 16 * i + quad * 4 + r;
                Yp[(((size_t)half * 4 + b) * CI_ + ci) * N_ + n] = yacc[i][t][r];
            }
        }
    if (quad == 0) {
#pragma unroll
        for (int t = 0; t < 2; t++) {
            int q = n0 + 32 * w + 16 * t + ql;
            ml[(((size_t)half * 4 + b) * N_ + q) * 2]     = mrun[t];
            ml[(((size_t)half * 4 + b) * N_ + q) * 2 + 1] = lrun[t];
        }
    }
}

// ---------------- K4: merge split-K halves -> y fp32 [b][ci][n] ----------
__global__ __launch_bounds__(256) void merge(const float* __restrict__ Yp,
                                             const float* __restrict__ ml,
                                             float* __restrict__ y) {
    int n  = blockIdx.x * 256 + threadIdx.x;
    int ci = blockIdx.y;
    int b  = blockIdx.z;
    float m0 = ml[((size_t)b * N_ + n) * 2];
    float l0 = ml[((size_t)b * N_ + n) * 2 + 1];
    float m1 = ml[(((size_t)4 + b) * N_ + n) * 2];
    float l1 = ml[(((size_t)4 + b) * N_ + n) * 2 + 1];
    float mm = fmaxf(m0, m1);
    float e0 = __expf(m0 - mm), e1 = __expf(m1 - mm);
    float num = e0 * Yp[((size_t)b * CI_ + ci) * N_ + n]
              + e1 * Yp[(((size_t)4 + b) * CI_ + ci) * N_ + n];
    y[((size_t)b * CI_ + ci) * N_ + n] = num / (e0 * l0 + e1 * l1);
}

// ---------------- K5: W conv + BN partial sums ---------------------------
__global__ __launch_bounds__(256) void wconv_stats(const float* __restrict__ y,
                                                   const float* __restrict__ Ww,
                                                   const float* __restrict__ Wb,
                                                   float* __restrict__ wy,
                                                   float* __restrict__ sums) {
    int n   = blockIdx.x * 256 + threadIdx.x;
    int co0 = blockIdx.y * 8;
    int b   = blockIdx.z;
    const float* yb = y + (size_t)b * CI_ * N_;
    float acc[8];
#pragma unroll
    for (int k = 0; k < 8; k++) acc[k] = Wb[co0 + k];
    for (int o = 0; o < CI_; o++) {
        float yv = yb[o * N_ + n];
#pragma unroll
        for (int k = 0; k < 8; k++) acc[k] += Ww[(co0 + k) * CI_ + o] * yv;
    }
    float* wyb = wy + (size_t)b * C_ * N_;
#pragma unroll
    for (int k = 0; k < 8; k++) wyb[(co0 + k) * N_ + n] = acc[k];

    __shared__ float wred[16][4];
    int lane = threadIdx.x & 63, wid = threadIdx.x >> 6;
#pragma unroll
    for (int k = 0; k < 8; k++) {
        float v1 = acc[k], v2 = acc[k] * acc[k];
#pragma unroll
        for (int off = 32; off > 0; off >>= 1) {
            v1 += __shfl_down(v1, off, 64);
            v2 += __shfl_down(v2, off, 64);
        }
        if (lane == 0) { wred[k][wid] = v1; wred[8 + k][wid] = v2; }
    }
    __syncthreads();
    if (threadIdx.x < 16) {
        int q = threadIdx.x;
        float t = wred[q][0] + wred[q][1] + wred[q][2] + wred[q][3];
        int k = q & 7;
        if (q < 8) atomicAdd(&sums[co0 + k], t);
        else       atomicAdd(&sums[256 + co0 + k], t);
    }
}

// ---------------- K6: BN finalize + residual -----------------------------
__global__ __launch_bounds__(256) void bn_finalize(const float* __restrict__ wy,
                                                   const float* __restrict__ x,
                                                   const float* __restrict__ sums,
                                                   const float* __restrict__ gamma,
                                                   const float* __restrict__ beta,
                                                   float* __restrict__ out) {
    int n  = blockIdx.x * 256 + threadIdx.x;
    int co = blockIdx.y;
    int b  = blockIdx.z;
    float cnt  = (float)(B_ * N_);
    float mean = sums[co] / cnt;
    float var  = sums[256 + co] / cnt - mean * mean;
    float sc   = rsqrtf(var + EPS_) * gamma[co];
    size_t idx = ((size_t)b * C_ + co) * N_ + n;
    out[idx] = (wy[idx] - mean) * sc + beta[co] + x[idx];
}

extern "C" void kernel_launch(void* const* d_in, const int* in_sizes, int n_in,
                              void* d_out, int out_size, void* d_ws, size_t ws_size,
                              hipStream_t stream) {
    const float* x     = (const float*)d_in[0];
    const float* gw    = (const float*)d_in[1];
    const float* gb    = (const float*)d_in[2];
    const float* Ww    = (const float*)d_in[3];
    const float* Wb    = (const float*)d_in[4];
    const float* gamma = (const float*)d_in[5];
    const float* beta  = (const float*)d_in[6];
    float* out = (float*)d_out;
    float* ws  = (float*)d_ws;

    // ws budget (floats): total 7,406,080 = 29.6 MB (< round-1's proven 33.6 MB)
    unsigned short* xt  = (unsigned short*)ws;              // [0, 2,097,152) as floats
    unsigned short* gxb = (unsigned short*)(ws + 2097152);  // [2,097,152, 3,145,728)
    float* Yp   = ws + 3145728;                             // [3,145,728, 7,340,032)
    float* wy   = Yp;                                       // Yp dead after merge
    float* ml   = ws + 7340032;                             // [7,340,032, 7,405,568)
    float* sums = ws + 7405568;                             // + 512
    float* y    = ws;                                       // aliases xt (dead after attn)

    hipLaunchKernelGGL(zero_acc, dim3(1), dim3(256), 0, stream, sums);
    hipLaunchKernelGGL(make_xt, dim3(16, 32, 4), dim3(256), 0, stream, x, xt);
    hipLaunchKernelGGL(gconv, dim3(16, 8, 4), dim3(256), 0, stream, xt, gw, gb, gxb);
    hipLaunchKernelGGL(attn, dim3(256), dim3(256), 0, stream, xt, gxb, Yp, ml);
    hipLaunchKernelGGL(merge, dim3(16, 128, 4), dim3(256), 0, stream, Yp, ml, y);
    hipLaunchKernelGGL(wconv_stats, dim3(16, 32, 4), dim3(256), 0, stream, y, Ww, Wb, wy, sums);
    hipLaunchKernelGGL(bn_finalize, dim3(16, 256, 4), dim3(256), 0, stream, wy, x, sums, gamma, beta, out);
}